// Round 2
// baseline (112.685 us; speedup 1.0000x reference)
//
#include <hip/hip_runtime.h>
#include <math.h>

// SANet attention: MFMA flash, LDS-staged K/V (xor-swizzled), 32 q-rows/wave,
// split-K, f16 partials. b=4, c=64, HW=4096, fp32 in/out.
//
// R6 post-mortem (44.8us attn): Occupancy 15.7% (grid 512 = 2 blocks/CU hard
// cap), VALUBusy 49%, MfmaUtil 14% -> pipes serialize at 2 waves/SIMD.
// R7: (1) P^T redistribution in-register via v_permlane16/32_swap + cvt_pkrtz
//     (kills Ps LDS roundtrip: -12 LDS ops/tile, -18KB LDS -> 32KB/block);
// (2) SPLITS 4->8, launch_bounds(256,4) -> 1024 blocks = 4 blocks/CU;
// (3) lsum via all-ones-A MFMA (VALU->MFMA pipe), defer-max THR=6 skips
//     rescale on most tiles; max-reduce via permlane swaps (off LDS pipe).
//
// mfma_f32_16x16x32_f16: A[m=lane&15][k=quad*8+j], B[k=quad*8+j][n=lane&15],
// D[m=quad*4+reg][n=lane&15]  (quad = lane>>4).
// S-mfma computes S^T tile (m=k_key, n=q); PV computes O^T (m=c, n=q).
//
// P redistribution algebra: source lane (quad qs) reg (m,r) holds key
// m*16+qs*4+r. Target lane (quad Q) word pairs: with A_m=pk(sv[m][0],sv[m][1]),
// B_m=pk(sv[m][2],sv[m][3]):  (w0,w2) = pl16swap(pl32swap(A_L, A_H)),
// (w1,w3) likewise from B. (pl32: vdst.hi<->vsrc.lo; pl16: vdst.odd-rows<->
// vsrc.even-rows; both return {vdst',vsrc'}.)

#define Bb 4
#define Cc 64
#define HWs 4096
#define RLOG2E 1.44269504088896340736f
#define DEFER_THR 6.0f

typedef _Float16 half8 __attribute__((ext_vector_type(8)));
typedef _Float16 half4 __attribute__((ext_vector_type(4)));
typedef float floatx4 __attribute__((ext_vector_type(4)));
typedef unsigned uint2v __attribute__((ext_vector_type(2)));

// ---------------- prep: content copy + Vt convert + Kt transpose ----------------
__global__ __launch_bounds__(256) void prep_k(const float* __restrict__ content,
                                              const float* __restrict__ Fs,
                                              const float* __restrict__ Fst,
                                              float* __restrict__ out,
                                              _Float16* __restrict__ Kt,
                                              _Float16* __restrict__ Vt) {
    const int bid = blockIdx.x;
    const int t = threadIdx.x;
    if (bid < 1024) {
        // content copy (float4) + V f16 convert (same linear layout)
        int i4 = bid * 256 + t;                       // 0..262143
        const float4* c4 = (const float4*)content;
        const float4* v4 = (const float4*)Fst;
        float4* o4 = (float4*)out;
        int b = i4 >> 16, rem = i4 & 65535;
        o4[(size_t)b * 131072 + rem] = c4[i4];        // out batch stride 2*64*4096 f32
        float4 v = v4[i4];
        half4 h;
        h[0] = (_Float16)v.x; h[1] = (_Float16)v.y;
        h[2] = (_Float16)v.z; h[3] = (_Float16)v.w;
        *(half4*)(Vt + (size_t)i4 * 4) = h;
    } else {
        // transpose+convert one 16hw x 64c tile of Fs -> Kt[b][k][c]
        __shared__ _Float16 T[16][72];
        int e = bid - 1024;                           // 0..1023
        int b = e >> 8;
        int hw0 = (e & 255) * 16;
        const float* sb = Fs + (size_t)b * Cc * HWs;
        {
            int c = t >> 2, x4 = (t & 3) * 4;         // 256 float4 = whole tile
            float4 v = *(const float4*)(sb + (size_t)c * HWs + hw0 + x4);
            T[x4 + 0][c] = (_Float16)v.x;
            T[x4 + 1][c] = (_Float16)v.y;
            T[x4 + 2][c] = (_Float16)v.z;
            T[x4 + 3][c] = (_Float16)v.w;
        }
        __syncthreads();
        if (t < 128) {
            int row = t >> 3, g = t & 7;
            _Float16* db = Kt + (size_t)b * HWs * Cc;
            *(half8*)(db + (size_t)(hw0 + row) * Cc + g * 8) = *(half8*)&T[row][g * 8];
        }
    }
}

// ---------------- attn: flash, LDS tiles, 32 q/wave, reg-space P shuffle ----------------
template <int NS>
__global__ __launch_bounds__(256, 4) void attn_k(const float* __restrict__ Fc,
                                                 const _Float16* __restrict__ Kt,
                                                 const _Float16* __restrict__ Vt,
                                                 _Float16* __restrict__ Opart,
                                                 float2* __restrict__ ml) {
    constexpr int TPS = 64 / NS;                  // k-tiles per split
    const int tid  = threadIdx.x;                 // 0..255
    const int w    = tid >> 6;                    // wave 0..3
    const int lane = tid & 63;
    const int quad = lane >> 4;
    const int l15  = lane & 15;
    // block: [split][b][qgroup]
    const int qg = blockIdx.x & 31;
    const int b  = (blockIdx.x >> 5) & 3;
    const int s  = blockIdx.x >> 7;
    const int k0base = s * TPS * 64;
    const int qA = qg * 128 + w * 32 + l15;       // group 0 q-row
    const int qB = qA + 16;                       // group 1 q-row

    // xor-swizzled tiles: 16B chunk j of row r stored at chunk j^(r&7)
    __shared__ _Float16 Kl[2][64 * 64];
    __shared__ _Float16 Vl[2][64 * 64];

    const float*    Fcb = Fc + (size_t)b * Cc * HWs;
    const _Float16* Kb  = Kt + (size_t)b * HWs * Cc;
    const _Float16* Vb  = Vt + (size_t)b * Cc * HWs;

    // staging role: tids 0..127 stage K, 128..255 stage V; 4 chunks each
    const bool isK  = tid < 128;
    const int  sl   = tid & 127;
    const int  srow = sl >> 3;                    // 0..15 (+16i)
    const int  sjg  = sl & 7;                     // global 16B chunk in row
    const int  ssw  = (sjg ^ (srow & 7)) * 8;     // swizzled chunk offset (halfs)

    // Q B-frags from fp32 Fc, pre-scaled by log2e (one-time strided loads)
    half8 qf[2][2];
    #pragma unroll
    for (int j = 0; j < 8; ++j) {
        qf[0][0][j] = (_Float16)(Fcb[(size_t)(quad * 8 + j) * HWs + qA] * RLOG2E);
        qf[0][1][j] = (_Float16)(Fcb[(size_t)(32 + quad * 8 + j) * HWs + qA] * RLOG2E);
        qf[1][0][j] = (_Float16)(Fcb[(size_t)(quad * 8 + j) * HWs + qB] * RLOG2E);
        qf[1][1][j] = (_Float16)(Fcb[(size_t)(32 + quad * 8 + j) * HWs + qB] * RLOG2E);
    }

    half8 st[4];
    auto stage_load = [&](int kt) {
        int kk0 = k0base + kt * 64;
        #pragma unroll
        for (int i = 0; i < 4; ++i) {
            int row = srow + 16 * i;
            if (isK) st[i] = *(const half8*)(Kb + (size_t)(kk0 + row) * 64 + sjg * 8);
            else     st[i] = *(const half8*)(Vb + (size_t)row * HWs + kk0 + sjg * 8);
        }
    };
    auto stage_write = [&](int p) {
        #pragma unroll
        for (int i = 0; i < 4; ++i) {
            int row = srow + 16 * i;
            if (isK) *(half8*)&Kl[p][row * 64 + ssw] = st[i];
            else     *(half8*)&Vl[p][row * 64 + ssw] = st[i];
        }
    };

    floatx4 acc[2][4];
    floatx4 accl[2];                              // SUM(P) via ones-A mfma
    #pragma unroll
    for (int g = 0; g < 2; ++g) {
        accl[g] = (floatx4)(0.0f);
        #pragma unroll
        for (int m = 0; m < 4; ++m) acc[g][m] = (floatx4)(0.0f);
    }
    float m_run[2] = {-INFINITY, -INFINITY};

    half8 vone;
    #pragma unroll
    for (int j = 0; j < 8; ++j) vone[j] = (_Float16)1.0f;

    stage_load(0);
    stage_write(0);
    stage_load(1);
    __syncthreads();

    const int swl = (l15 & 7);
    for (int kt = 0; kt < TPS; ++kt) {
        const int p = kt & 1;
        if (kt + 1 < TPS) stage_write(p ^ 1);
        if (kt + 2 < TPS) stage_load(kt + 2);

        // S^T = K . Q  (per-m ka liveness: 8 regs, not 32)
        floatx4 sv[2][4];
        #pragma unroll
        for (int m = 0; m < 4; ++m) {
            const half8 ka0 = *(const half8*)&Kl[p][(m * 16 + l15) * 64 + ((quad ^ swl) * 8)];
            const half8 ka1 = *(const half8*)&Kl[p][(m * 16 + l15) * 64 + (((4 + quad) ^ swl) * 8)];
            sv[0][m] = __builtin_amdgcn_mfma_f32_16x16x32_f16(ka0, qf[0][0], (floatx4)(0.0f), 0, 0, 0);
            sv[0][m] = __builtin_amdgcn_mfma_f32_16x16x32_f16(ka1, qf[0][1], sv[0][m], 0, 0, 0);
            sv[1][m] = __builtin_amdgcn_mfma_f32_16x16x32_f16(ka0, qf[1][0], (floatx4)(0.0f), 0, 0, 0);
            sv[1][m] = __builtin_amdgcn_mfma_f32_16x16x32_f16(ka1, qf[1][1], sv[1][m], 0, 0, 0);
        }

        // online softmax per q-group (log2 domain), P -> B-frags in registers
        half8 pb[2][2];
        #pragma unroll
        for (int g = 0; g < 2; ++g) {
            float mx = sv[g][0][0];
            #pragma unroll
            for (int m = 0; m < 4; ++m)
                #pragma unroll
                for (int r = 0; r < 4; ++r) mx = fmaxf(mx, sv[g][m][r]);
            // cross-quad max reduce via permlane swaps (VALU pipe, not LDS)
            {
                unsigned mu = __float_as_uint(mx);
                uint2v t32 = __builtin_amdgcn_permlane32_swap(mu, mu, false, false);
                mx = fmaxf(__uint_as_float(t32[0]), __uint_as_float(t32[1]));
                mu = __float_as_uint(mx);
                uint2v t16 = __builtin_amdgcn_permlane16_swap(mu, mu, false, false);
                mx = fmaxf(__uint_as_float(t16[0]), __uint_as_float(t16[1]));
            }
            // defer-max: only rescale when some lane grew past THR (P <= 2^THR = 64)
            if (!__all(mx - m_run[g] <= DEFER_THR)) {
                float m_new = fmaxf(m_run[g], mx);
                float alpha = exp2f(m_run[g] - m_new);   // 0 on first tile
                m_run[g] = m_new;
                #pragma unroll
                for (int m = 0; m < 4; ++m) acc[g][m] *= alpha;
                accl[g] *= alpha;
            }
            const float mb = m_run[g];
            unsigned Ap[4], Bp[4];
            #pragma unroll
            for (int m = 0; m < 4; ++m) {
                float e0 = exp2f(sv[g][m][0] - mb);
                float e1 = exp2f(sv[g][m][1] - mb);
                float e2 = exp2f(sv[g][m][2] - mb);
                float e3 = exp2f(sv[g][m][3] - mb);
                Ap[m] = __builtin_bit_cast(unsigned, __builtin_amdgcn_cvt_pkrtz(e0, e1));
                Bp[m] = __builtin_bit_cast(unsigned, __builtin_amdgcn_cvt_pkrtz(e2, e3));
            }
            // D-layout -> B-layout across quads: 2 swaps per word-pair
            unsigned pw[2][4];
            { uint2v a = __builtin_amdgcn_permlane32_swap(Ap[0], Ap[1], false, false);
              uint2v u = __builtin_amdgcn_permlane16_swap(a[0], a[1], false, false);
              pw[0][0] = u[0]; pw[0][2] = u[1]; }
            { uint2v a = __builtin_amdgcn_permlane32_swap(Bp[0], Bp[1], false, false);
              uint2v u = __builtin_amdgcn_permlane16_swap(a[0], a[1], false, false);
              pw[0][1] = u[0]; pw[0][3] = u[1]; }
            { uint2v a = __builtin_amdgcn_permlane32_swap(Ap[2], Ap[3], false, false);
              uint2v u = __builtin_amdgcn_permlane16_swap(a[0], a[1], false, false);
              pw[1][0] = u[0]; pw[1][2] = u[1]; }
            { uint2v a = __builtin_amdgcn_permlane32_swap(Bp[2], Bp[3], false, false);
              uint2v u = __builtin_amdgcn_permlane16_swap(a[0], a[1], false, false);
              pw[1][1] = u[0]; pw[1][3] = u[1]; }
            #pragma unroll
            for (int ks = 0; ks < 2; ++ks) {
                union { unsigned u4[4]; half8 h; } z;
                z.u4[0] = pw[ks][0]; z.u4[1] = pw[ks][1];
                z.u4[2] = pw[ks][2]; z.u4[3] = pw[ks][3];
                pb[g][ks] = z.h;
            }
        }

        // O^T update: D[m=c][n=q]  (per-m va liveness: 8 regs)
        #pragma unroll
        for (int m = 0; m < 4; ++m) {
            const half8 va0 = *(const half8*)&Vl[p][(m * 16 + l15) * 64 + ((quad ^ swl) * 8)];
            const half8 va1 = *(const half8*)&Vl[p][(m * 16 + l15) * 64 + (((4 + quad) ^ swl) * 8)];
            acc[0][m] = __builtin_amdgcn_mfma_f32_16x16x32_f16(va0, pb[0][0], acc[0][m], 0, 0, 0);
            acc[0][m] = __builtin_amdgcn_mfma_f32_16x16x32_f16(va1, pb[0][1], acc[0][m], 0, 0, 0);
            acc[1][m] = __builtin_amdgcn_mfma_f32_16x16x32_f16(va0, pb[1][0], acc[1][m], 0, 0, 0);
            acc[1][m] = __builtin_amdgcn_mfma_f32_16x16x32_f16(va1, pb[1][1], acc[1][m], 0, 0, 0);
        }
        // row-sum of P on the matrix pipe (all rows of D identical)
        accl[0] = __builtin_amdgcn_mfma_f32_16x16x32_f16(vone, pb[0][0], accl[0], 0, 0, 0);
        accl[0] = __builtin_amdgcn_mfma_f32_16x16x32_f16(vone, pb[0][1], accl[0], 0, 0, 0);
        accl[1] = __builtin_amdgcn_mfma_f32_16x16x32_f16(vone, pb[1][0], accl[1], 0, 0, 0);
        accl[1] = __builtin_amdgcn_mfma_f32_16x16x32_f16(vone, pb[1][1], accl[1], 0, 0, 0);

        __syncthreads();                          // one barrier per tile
    }

    // write partials (f16) + (M,l); lsum comes from accl (no shfl reduce needed)
    _Float16* op = Opart + ((size_t)(s * Bb + b) * Cc) * HWs;
    #pragma unroll
    for (int g = 0; g < 2; ++g) {
        int q = (g == 0) ? qA : qB;
        #pragma unroll
        for (int m = 0; m < 4; ++m)
            #pragma unroll
            for (int r = 0; r < 4; ++r) {
                int c = m * 16 + quad * 4 + r;
                op[(size_t)c * HWs + q] = (_Float16)acc[g][m][r];
            }
        if (quad == 0)
            ml[((size_t)b * HWs + q) * NS + s] = make_float2(m_run[g], accl[g][0]);
    }
}

// ---------------- combine: merge splits (exp2 domain) ----------------
template <int NS>
__global__ __launch_bounds__(256) void combine_k(const _Float16* __restrict__ Opart,
                                                 const float2* __restrict__ ml,
                                                 float* __restrict__ out) {
    int idx = blockIdx.x * 256 + threadIdx.x;     // over 4*64*4096 = 1M
    int q = idx & 4095;
    int c = (idx >> 12) & 63;
    int b = idx >> 18;
    const float2* mlp = ml + ((size_t)b * HWs + q) * NS;
    float2 mls[NS];
    #pragma unroll
    for (int s = 0; s < NS; ++s) mls[s] = mlp[s];
    float M = -INFINITY;
    #pragma unroll
    for (int s = 0; s < NS; ++s) M = fmaxf(M, mls[s].x);
    float l = 0.0f, o = 0.0f;
    #pragma unroll
    for (int s = 0; s < NS; ++s) {
        float wgt = exp2f(mls[s].x - M);
        l += wgt * mls[s].y;
        o += wgt * (float)Opart[(((size_t)s * Bb + b) * Cc + c) * HWs + q];
    }
    out[((size_t)b * 2 * Cc + Cc + c) * HWs + q] = o / l;
}

extern "C" void kernel_launch(void* const* d_in, const int* in_sizes, int n_in,
                              void* d_out, int out_size, void* d_ws, size_t ws_size,
                              hipStream_t stream) {
    const float* content   = (const float*)d_in[0];
    const float* content_s = (const float*)d_in[1];
    const float* style     = (const float*)d_in[2];
    float* out = (float*)d_out;

    _Float16* Kt = (_Float16*)d_ws;                           // [4][4096][64] f16  (2 MB)
    _Float16* Vt = Kt + (size_t)Bb * HWs * Cc;                // [4][64][4096] f16  (2 MB)
    _Float16* Opart = Vt + (size_t)Bb * Cc * HWs;             // [NS][4][64][4096] f16

    const size_t base = (size_t)2 * Bb * HWs * Cc * sizeof(_Float16);
    const size_t need8 = base + (size_t)8 * Bb * Cc * HWs * sizeof(_Float16)
                              + (size_t)Bb * HWs * 8 * sizeof(float2);
    const int ns = (ws_size >= need8) ? 8 : 4;
    float2* ml = (float2*)(Opart + (size_t)ns * Bb * Cc * HWs);

    prep_k<<<dim3(2048), dim3(256), 0, stream>>>(content, content_s, style, out, Kt, Vt);
    if (ns == 8) {
        attn_k<8><<<dim3(8 * Bb * 32), dim3(256), 0, stream>>>(content, Kt, Vt, Opart, ml);
        combine_k<8><<<dim3(4096), dim3(256), 0, stream>>>(Opart, ml, out);
    } else {
        attn_k<4><<<dim3(4 * Bb * 32), dim3(256), 0, stream>>>(content, Kt, Vt, Opart, ml);
        combine_k<4><<<dim3(4096), dim3(256), 0, stream>>>(Opart, ml, out);
    }
}

// Round 3
// 111.154 us; speedup vs baseline: 1.0138x; 1.0138x over previous
//
#include <hip/hip_runtime.h>
#include <math.h>

// SANet attention: MFMA flash, global_load_lds-staged K/V (source-preswizzled),
// 32 q-rows/wave, split-K, f16 partials. b=4, c=64, HW=4096, fp32 in/out.
//
// R7 post-mortem (112.7us total, attn sub-45): LB(256,4) forced VGPR<=128 but
// reg tally (~145 incl st[4]+accl+vone) => in-loop scratch spills ate the
// occupancy win. R8: (1) staging via __builtin_amdgcn_global_load_lds width=16
//     -> kills st[4] (16 VGPR), 4 ds_write_b128/lane/tile, staging addr VALU.
//     Swizzle kept via rule#21: linear LDS dest + inverse-swizzled global src
//     (chunk lj^lrow of each 128B row); read side unchanged.
// (2) lsum back on VALU (drop accl+vone, -12 VGPR). Peak live ~115 < 128.
// (3) s_setprio(1) around MFMA clusters (T5, attn-positive).
// Double-buffer correctness: compiler drains vmcnt(0) before each s_barrier.
//
// mfma_f32_16x16x32_f16: A[m=lane&15][k=quad*8+j], B[k=quad*8+j][n=lane&15],
// D[m=quad*4+reg][n=lane&15]  (quad = lane>>4).
// S-mfma computes S^T tile (m=k_key, n=q); PV computes O^T (m=c, n=q).
//
// P redistribution (verified R7): with A_m=pk(sv[m][0],sv[m][1]),
// B_m=pk(sv[m][2],sv[m][3]):  (w0,w2)=pl16swap(pl32swap(A_L,A_H)),
// (w1,w3) likewise from B.

#define Bb 4
#define Cc 64
#define HWs 4096
#define RLOG2E 1.44269504088896340736f
#define DEFER_THR 6.0f

typedef _Float16 half8 __attribute__((ext_vector_type(8)));
typedef _Float16 half4 __attribute__((ext_vector_type(4)));
typedef float floatx4 __attribute__((ext_vector_type(4)));
typedef unsigned uint2v __attribute__((ext_vector_type(2)));

// ---------------- prep: content copy + Vt convert + Kt transpose ----------------
__global__ __launch_bounds__(256) void prep_k(const float* __restrict__ content,
                                              const float* __restrict__ Fs,
                                              const float* __restrict__ Fst,
                                              float* __restrict__ out,
                                              _Float16* __restrict__ Kt,
                                              _Float16* __restrict__ Vt) {
    const int bid = blockIdx.x;
    const int t = threadIdx.x;
    if (bid < 1024) {
        // content copy (float4) + V f16 convert (same linear layout)
        int i4 = bid * 256 + t;                       // 0..262143
        const float4* c4 = (const float4*)content;
        const float4* v4 = (const float4*)Fst;
        float4* o4 = (float4*)out;
        int b = i4 >> 16, rem = i4 & 65535;
        o4[(size_t)b * 131072 + rem] = c4[i4];        // out batch stride 2*64*4096 f32
        float4 v = v4[i4];
        half4 h;
        h[0] = (_Float16)v.x; h[1] = (_Float16)v.y;
        h[2] = (_Float16)v.z; h[3] = (_Float16)v.w;
        *(half4*)(Vt + (size_t)i4 * 4) = h;
    } else {
        // transpose+convert one 16hw x 64c tile of Fs -> Kt[b][k][c]
        __shared__ _Float16 T[16][72];
        int e = bid - 1024;                           // 0..1023
        int b = e >> 8;
        int hw0 = (e & 255) * 16;
        const float* sb = Fs + (size_t)b * Cc * HWs;
        {
            int c = t >> 2, x4 = (t & 3) * 4;         // 256 float4 = whole tile
            float4 v = *(const float4*)(sb + (size_t)c * HWs + hw0 + x4);
            T[x4 + 0][c] = (_Float16)v.x;
            T[x4 + 1][c] = (_Float16)v.y;
            T[x4 + 2][c] = (_Float16)v.z;
            T[x4 + 3][c] = (_Float16)v.w;
        }
        __syncthreads();
        if (t < 128) {
            int row = t >> 3, g = t & 7;
            _Float16* db = Kt + (size_t)b * HWs * Cc;
            *(half8*)(db + (size_t)(hw0 + row) * Cc + g * 8) = *(half8*)&T[row][g * 8];
        }
    }
}

// ---------------- attn: flash, gload_lds tiles, 32 q/wave, reg-space P shuffle ----------------
template <int NS>
__global__ __launch_bounds__(256, 4) void attn_k(const float* __restrict__ Fc,
                                                 const _Float16* __restrict__ Kt,
                                                 const _Float16* __restrict__ Vt,
                                                 _Float16* __restrict__ Opart,
                                                 float2* __restrict__ ml) {
    constexpr int TPS = 64 / NS;                  // k-tiles per split
    const int tid  = threadIdx.x;                 // 0..255
    const int w    = tid >> 6;                    // wave 0..3
    const int lane = tid & 63;
    const int quad = lane >> 4;
    const int l15  = lane & 15;
    // block: [split][b][qgroup]
    const int qg = blockIdx.x & 31;
    const int b  = (blockIdx.x >> 5) & 3;
    const int s  = blockIdx.x >> 7;
    const int k0base = s * TPS * 64;
    const int qA = qg * 128 + w * 32 + l15;       // group 0 q-row
    const int qB = qA + 16;                       // group 1 q-row

    // xor-swizzled tiles: 16B chunk j of row r stored at chunk j^(r&7)
    __shared__ _Float16 Kl[2][64 * 64];
    __shared__ _Float16 Vl[2][64 * 64];

    const float*    Fcb = Fc + (size_t)b * Cc * HWs;
    const _Float16* Kb  = Kt + (size_t)b * HWs * Cc;
    const _Float16* Vb  = Vt + (size_t)b * Cc * HWs;

    // direct global->LDS staging. lane = lrow*8+lj writes LDS [row][chunk lj]
    // (linear, base+lane*16); source points at global chunk lj^lrow -> data
    // lands xor-swizzled. Rows of Kt (64c) and Vt (hw-contig) are both 128B.
    const int lrow = lane >> 3;                   // 0..7
    const int lj   = lane & 7;
    const int lsw8 = (lj ^ lrow) * 8;             // swizzled source chunk (halfs)
    const int r0   = w * 16;                      // this wave's 16-row slice

    auto stage = [&](int kt, int p) {
        const int kk0 = k0base + kt * 64;
        #pragma unroll
        for (int c = 0; c < 2; ++c) {
            const int r = r0 + c * 8 + lrow;
            __builtin_amdgcn_global_load_lds(
                (const __attribute__((address_space(1))) void*)(Kb + (size_t)(kk0 + r) * 64 + lsw8),
                (__attribute__((address_space(3))) void*)&Kl[p][(r0 + c * 8) * 64],
                16, 0, 0);
            __builtin_amdgcn_global_load_lds(
                (const __attribute__((address_space(1))) void*)(Vb + (size_t)r * HWs + kk0 + lsw8),
                (__attribute__((address_space(3))) void*)&Vl[p][(r0 + c * 8) * 64],
                16, 0, 0);
        }
    };

    // Q B-frags from fp32 Fc, pre-scaled by log2e (one-time strided loads)
    half8 qf[2][2];
    #pragma unroll
    for (int j = 0; j < 8; ++j) {
        qf[0][0][j] = (_Float16)(Fcb[(size_t)(quad * 8 + j) * HWs + qA] * RLOG2E);
        qf[0][1][j] = (_Float16)(Fcb[(size_t)(32 + quad * 8 + j) * HWs + qA] * RLOG2E);
        qf[1][0][j] = (_Float16)(Fcb[(size_t)(quad * 8 + j) * HWs + qB] * RLOG2E);
        qf[1][1][j] = (_Float16)(Fcb[(size_t)(32 + quad * 8 + j) * HWs + qB] * RLOG2E);
    }

    floatx4 acc[2][4];
    #pragma unroll
    for (int g = 0; g < 2; ++g)
        #pragma unroll
        for (int m = 0; m < 4; ++m) acc[g][m] = (floatx4)(0.0f);
    float m_run[2] = {-INFINITY, -INFINITY};
    float lsum[2] = {0.0f, 0.0f};

    stage(0, 0);
    __syncthreads();                              // compiler drains vmcnt first

    const int swl = (l15 & 7);
    for (int kt = 0; kt < TPS; ++kt) {
        const int p = kt & 1;
        if (kt + 1 < TPS) stage(kt + 1, p ^ 1);   // prefetch next tile (in flight across compute)

        // S^T = K . Q  (per-m ka liveness: 8 regs)
        floatx4 sv[2][4];
        __builtin_amdgcn_s_setprio(1);
        #pragma unroll
        for (int m = 0; m < 4; ++m) {
            const half8 ka0 = *(const half8*)&Kl[p][(m * 16 + l15) * 64 + ((quad ^ swl) * 8)];
            const half8 ka1 = *(const half8*)&Kl[p][(m * 16 + l15) * 64 + (((4 + quad) ^ swl) * 8)];
            sv[0][m] = __builtin_amdgcn_mfma_f32_16x16x32_f16(ka0, qf[0][0], (floatx4)(0.0f), 0, 0, 0);
            sv[0][m] = __builtin_amdgcn_mfma_f32_16x16x32_f16(ka1, qf[0][1], sv[0][m], 0, 0, 0);
            sv[1][m] = __builtin_amdgcn_mfma_f32_16x16x32_f16(ka0, qf[1][0], (floatx4)(0.0f), 0, 0, 0);
            sv[1][m] = __builtin_amdgcn_mfma_f32_16x16x32_f16(ka1, qf[1][1], sv[1][m], 0, 0, 0);
        }
        __builtin_amdgcn_s_setprio(0);

        // online softmax per q-group (log2 domain), P -> B-frags in registers
        half8 pb[2][2];
        #pragma unroll
        for (int g = 0; g < 2; ++g) {
            float mx = sv[g][0][0];
            #pragma unroll
            for (int m = 0; m < 4; ++m)
                #pragma unroll
                for (int r = 0; r < 4; ++r) mx = fmaxf(mx, sv[g][m][r]);
            // cross-quad max reduce via permlane swaps (VALU pipe, not LDS)
            {
                unsigned mu = __float_as_uint(mx);
                uint2v t32 = __builtin_amdgcn_permlane32_swap(mu, mu, false, false);
                mx = fmaxf(__uint_as_float(t32[0]), __uint_as_float(t32[1]));
                mu = __float_as_uint(mx);
                uint2v t16 = __builtin_amdgcn_permlane16_swap(mu, mu, false, false);
                mx = fmaxf(__uint_as_float(t16[0]), __uint_as_float(t16[1]));
            }
            // defer-max: only rescale when some lane grew past THR (P <= 2^THR = 64)
            if (!__all(mx - m_run[g] <= DEFER_THR)) {
                float m_new = fmaxf(m_run[g], mx);
                float alpha = exp2f(m_run[g] - m_new);   // 0 on first tile
                m_run[g] = m_new;
                #pragma unroll
                for (int m = 0; m < 4; ++m) acc[g][m] *= alpha;
                lsum[g] *= alpha;
            }
            const float mb = m_run[g];
            unsigned Ap[4], Bp[4];
            #pragma unroll
            for (int m = 0; m < 4; ++m) {
                float e0 = exp2f(sv[g][m][0] - mb);
                float e1 = exp2f(sv[g][m][1] - mb);
                float e2 = exp2f(sv[g][m][2] - mb);
                float e3 = exp2f(sv[g][m][3] - mb);
                lsum[g] += (e0 + e1) + (e2 + e3);
                Ap[m] = __builtin_bit_cast(unsigned, __builtin_amdgcn_cvt_pkrtz(e0, e1));
                Bp[m] = __builtin_bit_cast(unsigned, __builtin_amdgcn_cvt_pkrtz(e2, e3));
            }
            // D-layout -> B-layout across quads: 2 swaps per word-pair
            unsigned pw[2][4];
            { uint2v a = __builtin_amdgcn_permlane32_swap(Ap[0], Ap[1], false, false);
              uint2v u = __builtin_amdgcn_permlane16_swap(a[0], a[1], false, false);
              pw[0][0] = u[0]; pw[0][2] = u[1]; }
            { uint2v a = __builtin_amdgcn_permlane32_swap(Bp[0], Bp[1], false, false);
              uint2v u = __builtin_amdgcn_permlane16_swap(a[0], a[1], false, false);
              pw[0][1] = u[0]; pw[0][3] = u[1]; }
            { uint2v a = __builtin_amdgcn_permlane32_swap(Ap[2], Ap[3], false, false);
              uint2v u = __builtin_amdgcn_permlane16_swap(a[0], a[1], false, false);
              pw[1][0] = u[0]; pw[1][2] = u[1]; }
            { uint2v a = __builtin_amdgcn_permlane32_swap(Bp[2], Bp[3], false, false);
              uint2v u = __builtin_amdgcn_permlane16_swap(a[0], a[1], false, false);
              pw[1][1] = u[0]; pw[1][3] = u[1]; }
            #pragma unroll
            for (int ks = 0; ks < 2; ++ks) {
                union { unsigned u4[4]; half8 h; } z;
                z.u4[0] = pw[ks][0]; z.u4[1] = pw[ks][1];
                z.u4[2] = pw[ks][2]; z.u4[3] = pw[ks][3];
                pb[g][ks] = z.h;
            }
        }

        // O^T update: D[m=c][n=q]  (per-m va liveness: 8 regs)
        __builtin_amdgcn_s_setprio(1);
        #pragma unroll
        for (int m = 0; m < 4; ++m) {
            const half8 va0 = *(const half8*)&Vl[p][(m * 16 + l15) * 64 + ((quad ^ swl) * 8)];
            const half8 va1 = *(const half8*)&Vl[p][(m * 16 + l15) * 64 + (((4 + quad) ^ swl) * 8)];
            acc[0][m] = __builtin_amdgcn_mfma_f32_16x16x32_f16(va0, pb[0][0], acc[0][m], 0, 0, 0);
            acc[0][m] = __builtin_amdgcn_mfma_f32_16x16x32_f16(va1, pb[0][1], acc[0][m], 0, 0, 0);
            acc[1][m] = __builtin_amdgcn_mfma_f32_16x16x32_f16(va0, pb[1][0], acc[1][m], 0, 0, 0);
            acc[1][m] = __builtin_amdgcn_mfma_f32_16x16x32_f16(va1, pb[1][1], acc[1][m], 0, 0, 0);
        }
        __builtin_amdgcn_s_setprio(0);

        __syncthreads();                          // vmcnt drain + barrier: next tile ready
    }

    // reduce row-sums across quads (once), write partials (f16) + (M,l)
    _Float16* op = Opart + ((size_t)(s * Bb + b) * Cc) * HWs;
    #pragma unroll
    for (int g = 0; g < 2; ++g) {
        lsum[g] += __shfl_xor(lsum[g], 16);
        lsum[g] += __shfl_xor(lsum[g], 32);
        int q = (g == 0) ? qA : qB;
        #pragma unroll
        for (int m = 0; m < 4; ++m)
            #pragma unroll
            for (int r = 0; r < 4; ++r) {
                int c = m * 16 + quad * 4 + r;
                op[(size_t)c * HWs + q] = (_Float16)acc[g][m][r];
            }
        if (quad == 0)
            ml[((size_t)b * HWs + q) * NS + s] = make_float2(m_run[g], lsum[g]);
    }
}

// ---------------- combine: merge splits (exp2 domain) ----------------
template <int NS>
__global__ __launch_bounds__(256) void combine_k(const _Float16* __restrict__ Opart,
                                                 const float2* __restrict__ ml,
                                                 float* __restrict__ out) {
    int idx = blockIdx.x * 256 + threadIdx.x;     // over 4*64*4096 = 1M
    int q = idx & 4095;
    int c = (idx >> 12) & 63;
    int b = idx >> 18;
    const float2* mlp = ml + ((size_t)b * HWs + q) * NS;
    float2 mls[NS];
    #pragma unroll
    for (int s = 0; s < NS; ++s) mls[s] = mlp[s];
    float M = -INFINITY;
    #pragma unroll
    for (int s = 0; s < NS; ++s) M = fmaxf(M, mls[s].x);
    float l = 0.0f, o = 0.0f;
    #pragma unroll
    for (int s = 0; s < NS; ++s) {
        float wgt = exp2f(mls[s].x - M);
        l += wgt * mls[s].y;
        o += wgt * (float)Opart[(((size_t)s * Bb + b) * Cc + c) * HWs + q];
    }
    out[((size_t)b * 2 * Cc + Cc + c) * HWs + q] = o / l;
}

extern "C" void kernel_launch(void* const* d_in, const int* in_sizes, int n_in,
                              void* d_out, int out_size, void* d_ws, size_t ws_size,
                              hipStream_t stream) {
    const float* content   = (const float*)d_in[0];
    const float* content_s = (const float*)d_in[1];
    const float* style     = (const float*)d_in[2];
    float* out = (float*)d_out;

    _Float16* Kt = (_Float16*)d_ws;                           // [4][4096][64] f16  (2 MB)
    _Float16* Vt = Kt + (size_t)Bb * HWs * Cc;                // [4][64][4096] f16  (2 MB)
    _Float16* Opart = Vt + (size_t)Bb * Cc * HWs;             // [NS][4][64][4096] f16

    const size_t base = (size_t)2 * Bb * HWs * Cc * sizeof(_Float16);
    const size_t need8 = base + (size_t)8 * Bb * Cc * HWs * sizeof(_Float16)
                              + (size_t)Bb * HWs * 8 * sizeof(float2);
    const int ns = (ws_size >= need8) ? 8 : 4;
    float2* ml = (float2*)(Opart + (size_t)ns * Bb * Cc * HWs);

    prep_k<<<dim3(2048), dim3(256), 0, stream>>>(content, content_s, style, out, Kt, Vt);
    if (ns == 8) {
        attn_k<8><<<dim3(8 * Bb * 32), dim3(256), 0, stream>>>(content, Kt, Vt, Opart, ml);
        combine_k<8><<<dim3(4096), dim3(256), 0, stream>>>(Opart, ml, out);
    } else {
        attn_k<4><<<dim3(4 * Bb * 32), dim3(256), 0, stream>>>(content, Kt, Vt, Opart, ml);
        combine_k<4><<<dim3(4096), dim3(256), 0, stream>>>(Opart, ml, out);
    }
}